// Round 1
// baseline (77.335 us; speedup 1.0000x reference)
//
#include <hip/hip_runtime.h>

// Reference reduces algebraically to out[0, i, c] = b_gcn[c]:
//   adj = where(where(corr > 1.5, corr, 0) < -1.5, ..., 0) == 0 everywhere
//   (first where leaves only values >= 0; none are < -1.5)
//   => out = 0 @ (e @ W_gcn) + b_gcn = broadcast(b_gcn) over [1, N, OUT_GCN]
//
// So the whole kernel is an 8 MB bias broadcast. Memory/launch-overhead bound.

#define OUT_GCN 512
#define B4_PER_ROW (OUT_GCN / 4)   // 128 float4 per output row

__global__ void bias_broadcast_kernel(const float4* __restrict__ b4,
                                      float4* __restrict__ out4,
                                      int total4) {
    int i = blockIdx.x * blockDim.x + threadIdx.x;
    if (i < total4) {
        // out[row*512 + c] = b_gcn[c]  ->  out4[k] = b4[k & 127]
        out4[i] = b4[i & (B4_PER_ROW - 1)];
    }
}

extern "C" void kernel_launch(void* const* d_in, const int* in_sizes, int n_in,
                              void* d_out, int out_size, void* d_ws, size_t ws_size,
                              hipStream_t stream) {
    // setup_inputs order:
    // 0: spans_embeddings, 1: W_c1, 2: b_c1, 3: W_c2, 4: b_c2,
    // 5: W_link, 6: b_link, 7: W_gcn, 8: b_gcn
    const float* b_gcn = (const float*)d_in[8];
    float* out = (float*)d_out;

    int total4 = out_size / 4;               // 4096*512/4 = 524288 float4 stores
    dim3 block(256);
    dim3 grid((total4 + block.x - 1) / block.x);
    bias_broadcast_kernel<<<grid, block, 0, stream>>>(
        (const float4*)b_gcn, (float4*)out, total4);
}